// Round 9
// baseline (69.004 us; speedup 1.0000x reference)
//
#include <hip/hip_runtime.h>
#include <hip/hip_bf16.h>
#include <cstdint>
#include <cstddef>

typedef __attribute__((ext_vector_type(8))) short bf16x8;
typedef __attribute__((ext_vector_type(4))) float f32x4;

#define BATCH 8
#define NTOK 8192
#define LDIM 512
#define DDIM 128
#define NQ 16
#define NSEG 8
#define SEGLEN (NTOK / NSEG) /* 1024 */

static __device__ __forceinline__ short f2bf(float f) {
  uint32_t u = __float_as_uint(f);
  uint32_t r = u + 0x7fffu + ((u >> 16) & 1u); // RNE
  return (short)(r >> 16);
}

// hardware packed f32->bf16 (RNE)
static __device__ __forceinline__ bf16x8 cvt8(float4 a, float4 b) {
  union { uint32_t u[4]; bf16x8 v; } r;
  asm("v_cvt_pk_bf16_f32 %0, %1, %2" : "=v"(r.u[0]) : "v"(a.x), "v"(a.y));
  asm("v_cvt_pk_bf16_f32 %0, %1, %2" : "=v"(r.u[1]) : "v"(a.z), "v"(a.w));
  asm("v_cvt_pk_bf16_f32 %0, %1, %2" : "=v"(r.u[2]) : "v"(b.x), "v"(b.y));
  asm("v_cvt_pk_bf16_f32 %0, %1, %2" : "=v"(r.u[3]) : "v"(b.z), "v"(b.w));
  return r.v;
}

// pad-mask accessor robust to bool-ABI (byteFlag=1: 1B/elem, 0: int32/elem)
static __device__ __forceinline__ bool is_pad(const void* pad, int byteFlag, int j) {
  return byteFlag ? (((const unsigned char*)pad)[j] != 0)
                  : (((const int*)pad)[j] != 0);
}

// ---------------- k0: repack W1 -> MFMA B-frag order bf16; block 0 detects bool ABI ----------
// wfrag[(c*8 + t)*64 + lane][i] = bf16( W1[c*32 + (lane>>4)*8 + i][t*16 + (lane&15)] )
__global__ __launch_bounds__(256) void k0_wfrag(const float* __restrict__ W1,
                                                short* __restrict__ wfrag,
                                                const unsigned int* __restrict__ pad_raw,
                                                int* __restrict__ flag) {
  int tid = blockIdx.x * blockDim.x + threadIdx.x;
  if (tid < 16 * 8 * 64) {
    int l = tid & 63;
    int t = (tid >> 6) & 7;
    int c = tid >> 9;
    int kbase = c * 32 + (l >> 4) * 8;
    int col = t * 16 + (l & 15);
    bf16x8 frag;
#pragma unroll
    for (int i = 0; i < 8; ++i) frag[i] = f2bf(W1[(size_t)(kbase + i) * DDIM + col]);
    ((bf16x8*)wfrag)[tid] = frag;
  }
  if (blockIdx.x == 0) {
    int any_gt1 = 0;
    for (int i = threadIdx.x; i < 16384; i += 256)
      if (pad_raw[i] > 1u) any_gt1 = 1;
    unsigned long long m = __ballot(any_gt1);
    __shared__ int s[4];
    if ((threadIdx.x & 63) == 0) s[threadIdx.x >> 6] = (m != 0ull) ? 1 : 0;
    __syncthreads();
    if (threadIdx.x == 0) flag[0] = (s[0] | s[1] | s[2] | s[3]);
  }
}

// ---------------- k1: expw[row] = exp( tanh(x[row]W1)·W2 ) ----------------
// 256 thr (4 waves) x 16 rows/wave = 64 rows/block; grid 1024; 2 blocks/CU.
// BOTH W1 (32KB quarters) and x (8KB chunks) staged via global_load_lds, double-buffered.
// x LDS tile XOR-swizzled: linear LDS dest + pre-unswizzled global source + swizzled read.
__global__ __launch_bounds__(256, 2) void k1_scores(const float* __restrict__ x,
                                                    const short* __restrict__ wfrag,
                                                    const float* __restrict__ W2,
                                                    float* __restrict__ expw) {
  __shared__ __align__(16) char smem[81920]; // 64KB wfrag dbuf + 16KB x dbuf
  short* ldsw = (short*)smem;
  char* xchunk = smem + 65536;
  const int tid = threadIdx.x, wave = tid >> 6, lane = tid & 63;
  const int g = lane >> 4;
  const int rl = (wave << 4) + (lane & 15); // local row 0..63
  const int rowB = blockIdx.x * 64;

// stage 32KB wfrag quarter qd into buffer wb (256 thr x 8 x 16B, linear dest)
#define STAGE_W(qd, wb)                                                                     \
  {                                                                                         \
    const unsigned int* srcw_ = (const unsigned int*)wfrag + (qd) * 8192;                   \
    _Pragma("unroll")                                                                       \
    for (int i = 0; i < 8; ++i) {                                                           \
      int off_ = (i * 4 + wave) * 64 + lane;                                                \
      __builtin_amdgcn_global_load_lds(                                                     \
          (const __attribute__((address_space(1))) unsigned int*)(srcw_ + off_ * 4),        \
          (__attribute__((address_space(3))) unsigned int*)&ldsw[(wb) * 16384 + off_ * 8],  \
          16, 0, 0);                                                                        \
    }                                                                                       \
  }

// stage 8KB x chunk c (64 rows x 32 f32 cols) into x buffer xb; source pre-unswizzled
#define STAGE_X(c, xb)                                                                      \
  {                                                                                         \
    _Pragma("unroll")                                                                       \
    for (int k = 0; k < 2; ++k) {                                                           \
      int o_ = (wave << 11) + (k << 10) + (lane << 4); /* linear byte off in 8KB */         \
      int lo_ = o_ ^ (((o_ >> 7) & 7) << 4);           /* logical byte (involution) */      \
      int r_ = lo_ >> 7, cb_ = lo_ & 127;                                                   \
      const char* srcx_ =                                                                   \
          (const char*)x + ((size_t)(rowB + r_) * LDIM + (size_t)(c) * 32) * 4 + cb_;       \
      __builtin_amdgcn_global_load_lds(                                                     \
          (const __attribute__((address_space(1))) unsigned int*)srcx_,                     \
          (__attribute__((address_space(3))) unsigned int*)(xchunk + (xb) * 8192 + o_),     \
          16, 0, 0);                                                                        \
    }                                                                                       \
  }

  f32x4 acc[8];
#pragma unroll
  for (int t = 0; t < 8; ++t) acc[t] = (f32x4){0.f, 0.f, 0.f, 0.f};

  STAGE_W(0, 0);
  STAGE_X(0, 0);
  __syncthreads(); // prologue staged

  const int sw = (rl & 7) << 4;
  const int xrbase = rl * 128 + g * 32;

  for (int c = 0; c < 16; ++c) {
    if ((c & 3) == 0 && c < 12) STAGE_W((c >> 2) + 1, ((c >> 2) + 1) & 1); // next W quarter
    if (c < 15) STAGE_X(c + 1, (c + 1) & 1);                              // next x chunk
    const char* xc = xchunk + (c & 1) * 8192;
    float4 a0 = *(const float4*)(xc + (xrbase ^ sw));
    float4 a1 = *(const float4*)(xc + ((xrbase + 16) ^ sw));
    bf16x8 af = cvt8(a0, a1);
    const int wq = (c >> 2) & 1, cc = c & 3;
#pragma unroll
    for (int t = 0; t < 8; ++t) {
      bf16x8 bfr = *(const bf16x8*)&ldsw[wq * 16384 + ((cc * 8 + t) * 64 + lane) * 8];
      acc[t] = __builtin_amdgcn_mfma_f32_16x16x32_bf16(af, bfr, acc[t], 0, 0, 0);
    }
    if (c < 15) __syncthreads(); // next buffers staged + this chunk's reads done
  }

  // epilogue: tanh + dot W2 + 16-lane reduce; D layout col=lane&15(+16t), row=(lane>>4)*4+r
  float w2v[8];
#pragma unroll
  for (int t = 0; t < 8; ++t) w2v[t] = W2[t * 16 + (lane & 15)];
  float asum[4] = {0.f, 0.f, 0.f, 0.f};
#pragma unroll
  for (int t = 0; t < 8; ++t) {
#pragma unroll
    for (int r = 0; r < 4; ++r) {
      float h = 1.f - 2.f / (__expf(2.f * acc[t][r]) + 1.f); // tanh
      asum[r] += h * w2v[t];
    }
  }
#pragma unroll
  for (int m = 1; m < 16; m <<= 1) {
#pragma unroll
    for (int r = 0; r < 4; ++r) asum[r] += __shfl_xor(asum[r], m, 64);
  }
  if ((lane & 15) == 0) {
    int rb = rowB + wave * 16 + (lane >> 4) * 4;
#pragma unroll
    for (int r = 0; r < 4; ++r) expw[rb + r] = __expf(asum[r]); // unnormalized weight
  }
}

// ---------------- k3: pooling partials; register-carried compaction, 4x128 float4 accum ----
// grid ((b*16+q)*8+s) = 1024 blocks x 512 thr.
__global__ __launch_bounds__(512) void k3_pool(const float* __restrict__ x,
                                               const float* __restrict__ expw,
                                               const int* __restrict__ ids,
                                               const void* __restrict__ pad,
                                               const int* __restrict__ flag,
                                               float* __restrict__ partial,
                                               float* __restrict__ wsum) {
  int blk = blockIdx.x;
  int s = blk & 7, q = (blk >> 3) & 15, b = blk >> 7;
  int wave = threadIdx.x >> 6, lane = threadIdx.x & 63;
  int bfl = flag[0];
  __shared__ float w_u[1024];
  __shared__ unsigned short j_u[1024];
  __shared__ int cnt[8];
  __shared__ float wred[8];

  const int base = b * NTOK;
  const int tokBase = s * SEGLEN + wave * 128;

  // membership + weights, carried in registers across the count-sync
  int j0 = tokBase + lane, j1 = tokBase + 64 + lane;
  bool mem0 = (ids[base + j0] == q) && !is_pad(pad, bfl, base + j0);
  bool mem1 = (ids[base + j1] == q) && !is_pad(pad, bfl, base + j1);
  float wt0 = mem0 ? expw[base + j0] : 0.f;
  float wt1 = mem1 ? expw[base + j1] : 0.f;
  unsigned long long m0 = __ballot(mem0), m1 = __ballot(mem1);
  int c0w = __popcll(m0), c1w = __popcll(m1);
  if (lane == 0) cnt[wave] = c0w + c1w;
  __syncthreads();

  int wpos = 0;
#pragma unroll
  for (int w = 0; w < 8; ++w) if (w < wave) wpos += cnt[w];
  const int total = cnt[0] + cnt[1] + cnt[2] + cnt[3] + cnt[4] + cnt[5] + cnt[6] + cnt[7];

  unsigned long long below = (1ull << lane) - 1ull;
  if (mem0) {
    int pos = wpos + __popcll(m0 & below);
    w_u[pos] = wt0; j_u[pos] = (unsigned short)j0;
  }
  if (mem1) {
    int pos = wpos + c0w + __popcll(m1 & below);
    w_u[pos] = wt1; j_u[pos] = (unsigned short)j1;
  }
  float wacc = wt0 + wt1;
#pragma unroll
  for (int m = 1; m < 64; m <<= 1) wacc += __shfl_xor(wacc, m, 64);
  if (lane == 0) wred[wave] = wacc;
  __syncthreads();

  // accumulate: group grp walks its quarter of entries; 128 threads x float4 = 512 cols
  int grp = threadIdx.x >> 7, ct = threadIdx.x & 127;
  int c0 = ct * 4;
  int per = (total + 3) >> 2;
  int e0 = grp * per;
  int e1 = e0 + per; if (e1 > total) e1 = total;
  float4 av = {0.f, 0.f, 0.f, 0.f};
  if (e0 < e1) {
    float4 cur = *(const float4*)(x + (size_t)(base + j_u[e0]) * LDIM + c0);
    int e = e0;
    for (; e + 1 < e1; ++e) {
      float4 nxt = *(const float4*)(x + (size_t)(base + j_u[e + 1]) * LDIM + c0); // load-ahead
      float wt = w_u[e];
      av.x = fmaf(wt, cur.x, av.x); av.y = fmaf(wt, cur.y, av.y);
      av.z = fmaf(wt, cur.z, av.z); av.w = fmaf(wt, cur.w, av.w);
      cur = nxt;
    }
    float wt = w_u[e];
    av.x = fmaf(wt, cur.x, av.x); av.y = fmaf(wt, cur.y, av.y);
    av.z = fmaf(wt, cur.z, av.z); av.w = fmaf(wt, cur.w, av.w);
  }
  *(float4*)(partial + ((size_t)(blk * 4 + grp)) * LDIM + c0) = av;
  if (threadIdx.x == 0)
    wsum[blk] = wred[0] + wred[1] + wred[2] + wred[3] + wred[4] + wred[5] + wred[6] + wred[7];
}

// ---------------- k4: combine 32 partial slots per (b,q) + normalize ----------------
__global__ __launch_bounds__(512) void k4_reduce(const float* __restrict__ partial,
                                                 const float* __restrict__ wsum,
                                                 float* __restrict__ out) {
  int bq = blockIdx.x; // b*16+q
  int b = bq >> 4, q = bq & 15;
  int c = threadIdx.x;
  float ws = 0.f;
#pragma unroll
  for (int s = 0; s < 8; ++s) ws += wsum[b * 128 + q * 8 + s];
  float ps = 0.f;
#pragma unroll
  for (int s = 0; s < 8; ++s)
#pragma unroll
    for (int g = 0; g < 4; ++g)
      ps += partial[((size_t)((b * 128 + q * 8 + s) * 4 + g)) * LDIM + c];
  out[bq * 512 + c] = (ws > 0.f) ? (ps / ws) : 0.f;
}

extern "C" void kernel_launch(void* const* d_in, const int* in_sizes, int n_in,
                              void* d_out, int out_size, void* d_ws, size_t ws_size,
                              hipStream_t stream) {
  const float* x = (const float*)d_in[0];
  const float* W1 = (const float*)d_in[1];
  const float* W2 = (const float*)d_in[2];
  const int* ids = (const int*)d_in[3];
  const void* pad = d_in[4]; // bool ABI detected at runtime
  float* out = (float*)d_out;

  char* ws = (char*)d_ws;
  short* wfrag = (short*)ws;                 // 131072 B
  int* flag = (int*)(ws + 131072);           // 4 B
  float* expw = (float*)(ws + 131200);       // 262144 B
  float* wsum = (float*)(ws + 393344);       // 4096 B
  float* partial = (float*)(ws + 397440);    // 1024*4*512*4 = 8388608 B

  hipLaunchKernelGGL(k0_wfrag, dim3(32), dim3(256), 0, stream,
                     W1, wfrag, (const unsigned int*)pad, flag);
  hipLaunchKernelGGL(k1_scores, dim3((BATCH * NTOK) / 64), dim3(256), 0, stream,
                     x, wfrag, W2, expw);
  hipLaunchKernelGGL(k3_pool, dim3(BATCH * NQ * NSEG), dim3(512), 0, stream,
                     x, expw, ids, pad, flag, partial, wsum);
  hipLaunchKernelGGL(k4_reduce, dim3(BATCH * NQ), dim3(512), 0, stream,
                     partial, wsum, out);
}